// Round 13
// baseline (185.147 us; speedup 1.0000x reference)
//
#include <hip/hip_runtime.h>
#include <math.h>

#define B_ 4
#define N_ 8192
#define C_ 128
#define CN_ 64
#define M_ 32

#define ROR1 0x121
#define ROR2 0x122
#define ROR4 0x124
#define ROR8 0x128

typedef float f4 __attribute__((ext_vector_type(4)));
typedef float f2 __attribute__((ext_vector_type(2)));

__device__ __forceinline__ f4 ld4(const float* p) { return *(const f4*)p; }

template<int CTRL>
__device__ __forceinline__ float dpp_add(float x) {
    int y = __builtin_amdgcn_update_dpp(0, __float_as_int(x), CTRL, 0xF, 0xF, true);
    return x + __int_as_float(y);
}
template<int CTRL>
__device__ __forceinline__ float dpp_max(float x) {
    int y = __builtin_amdgcn_update_dpp(0, __float_as_int(x), CTRL, 0xF, 0xF, true);
    return fmaxf(x, __int_as_float(y));
}
__device__ __forceinline__ float red16_add(float x) {
    return dpp_add<ROR1>(dpp_add<ROR2>(dpp_add<ROR4>(dpp_add<ROR8>(x))));
}
__device__ __forceinline__ float red16_max(float x) {
    return dpp_max<ROR1>(dpp_max<ROR2>(dpp_max<ROR4>(dpp_max<ROR8>(x))));
}

__device__ __forceinline__ float dot4(f4 a, f4 b) {
    return a.x * b.x + a.y * b.y + a.z * b.z + a.w * b.w;
}

// ========== kA: 1024 self-contained pe blocks (pe stream + a/kb + vsum + softmax) ==========
__global__ __launch_bounds__(256, 4) void kA(const float* __restrict__ q,
                                             const float* __restrict__ k,
                                             const float* __restrict__ v,
                                             const float* __restrict__ pe,
                                             const float* __restrict__ Wq,
                                             const float* __restrict__ Wk,
                                             const float* __restrict__ w1,
                                             float* __restrict__ vsum_part,
                                             float* __restrict__ scl_g,
                                             float* __restrict__ pe_part) {
    __shared__ float lpd[4][256];              // 4 KB pdot staging
    __shared__ __align__(16) f4 lps4[4][256];  // 16 KB reduce buffer (pe + vsum rounds)
    __shared__ float pro[352];                 // wq1[128] wk1[128] aL[32] kbL[64]

    int g = blockIdx.x;
    int t = threadIdx.x;
    int lane = t & 63, wv = t >> 6;
    int b = g >> 8;
    int n0 = (g & 255) * 32;
    int grp = lane >> 4, li = lane & 15;
    float* wq1l = pro;
    float* wk1l = pro + 128;
    float* aL   = pro + 256;
    float* kbL  = pro + 288;

    // ---- weight fold (L2-resident) ----
    if (t < C_) {
        float s = 0.f;
        for (int c2 = 0; c2 < CN_; ++c2) s += Wq[t * CN_ + c2] * w1[c2];
        wq1l[t] = s;
    } else {
        int c = t - C_;
        float s = 0.f;
        for (int c2 = 0; c2 < CN_; ++c2) s += Wk[c * CN_ + c2] * w1[c2];
        wk1l[c] = s;
    }
    __syncthreads();

    f4 wq0 = *((const f4*)wq1l + li * 2);
    f4 wq1v = *((const f4*)wq1l + li * 2 + 1);
    f4 wk0 = *((const f4*)wk1l + li * 2);
    f4 wk1v = *((const f4*)wk1l + li * 2 + 1);
    f4 w1v = *((const f4*)w1 + li);

    f4 acc[8];
#pragma unroll
    for (int j = 0; j < 8; ++j) acc[j] = (f4){0.f, 0.f, 0.f, 0.f};
    f4 acc_v = (f4){0.f, 0.f, 0.f, 0.f};

    int nbase = n0 + wv * 8;
    const float* pbase = pe + ((size_t)b * N_ + (size_t)nbase) * 2048;
    int hv = lane >> 5, c4 = lane & 31;   // for vsum loads

    // ---- stream: 8 rows/wave with x[8] in flight; secondary loads interleaved ----
#pragma unroll
    for (int i = 0; i < 8; ++i) {
        const float* p = pbase + (size_t)i * 2048;
        f4 x[8];
#pragma unroll
        for (int j = 0; j < 8; ++j) x[j] = ld4(p + (j * 64 + lane) * 4);

        // issue secondary loads (overlap with pe latency)
        f4 s0, s1;
        bool svalid = false;
        if (i < 4) {
            int rl = wv * 16 + i * 4 + grp;       // halo row 0..63
            int jrow = n0 - 16 + rl;
            svalid = (jrow >= 0 && jrow < N_);
            const float* kr = k + ((size_t)b * N_ + (svalid ? jrow : 0)) * C_;
            s0 = ld4(kr + li * 8);
            s1 = ld4(kr + li * 8 + 4);
        } else if (i < 6) {
            int rl = wv * 8 + (i - 4) * 4 + grp;  // q row 0..31
            const float* qr = q + ((size_t)b * N_ + n0 + rl) * C_;
            s0 = ld4(qr + li * 8);
            s1 = ld4(qr + li * 8 + 4);
            svalid = true;
        } else {
            int r0 = wv * 8 + hv * 4 + (i - 6) * 2;
            s0 = ld4(v + ((size_t)b * N_ + n0 + r0) * C_ + c4 * 4);
            s1 = ld4(v + ((size_t)b * N_ + n0 + r0 + 1) * C_ + c4 * 4);
        }

        // consume pe
#pragma unroll
        for (int j = 0; j < 8; ++j) {
            acc[j] += x[j];
            float tv = dot4(x[j], w1v);
            tv = red16_add(tv);
            if (li == 0) lpd[wv][i * 32 + j * 4 + grp] = tv;
        }

        // consume secondary
        if (i < 4) {
            float tk = svalid ? (dot4(s0, wk0) + dot4(s1, wk1v)) : 0.f;
            tk = red16_add(tk);
            if (li == 0) kbL[wv * 16 + i * 4 + grp] = tk;
        } else if (i < 6) {
            float ta = dot4(s0, wq0) + dot4(s1, wq1v);
            ta = red16_add(ta);
            if (li == 0) aL[wv * 8 + (i - 4) * 4 + grp] = ta;
        } else {
            acc_v += s0;
            acc_v += s1;
        }
    }
    __syncthreads();   // aL/kbL complete (cross-wave reads in softmax)

    // ---- fused softmax ----
    {
        int hw = lane >> 5, m = lane & 31;
        float* sout = scl_g + ((size_t)b * N_ + (size_t)nbase) * M_;
#pragma unroll
        for (int ii = 0; ii < 4; ++ii) {
            int rl = ii * 2 + hw;
            int rb = wv * 8 + rl;
            float pd = lpd[wv][rl * 32 + m];
            float lg = aL[rb] + pd - kbL[rb + m];
            float mx = red16_max(lg);
            mx = fmaxf(mx, __shfl_xor(mx, 16));
            float e = __expf(lg - mx);
            float sm = red16_add(e);
            sm += __shfl_xor(sm, 16);
            sout[ii * 64 + lane] = e / sm;
        }
    }

    // ---- pe cross-wave reduce (two 16KB rounds) ----
    f4* ppg = (f4*)(pe_part + (size_t)g * 2048);
#pragma unroll
    for (int r = 0; r < 2; ++r) {
        __syncthreads();
#pragma unroll
        for (int jr = 0; jr < 4; ++jr) lps4[wv][jr * 64 + lane] = acc[r * 4 + jr];
        __syncthreads();
        f4 s = lps4[0][t];
        s += lps4[1][t];
        s += lps4[2][t];
        s += lps4[3][t];
        ppg[r * 256 + t] = s;
    }

    // ---- vsum block reduce ----
    __syncthreads();
    lps4[wv][hv * 32 + c4] = acc_v;
    __syncthreads();
    if (t < 32) {
        f4 s = (f4){0.f, 0.f, 0.f, 0.f};
#pragma unroll
        for (int w = 0; w < 4; ++w) s += lps4[w][t] + lps4[w][32 + t];
        *((f4*)(vsum_part + (size_t)g * C_) + t) = s;
    }
}

// ========== kR: S_sum[b,2048] over 256 partials ; vsum_final over 256 partials ==========
__global__ __launch_bounds__(256) void kR(const float* __restrict__ pe_part,
                                          const float* __restrict__ vsum_part,
                                          float* __restrict__ S_sum,
                                          float* __restrict__ vsum_final) {
    int g = blockIdx.x;
    int t = threadIdx.x;
    if (g < 256) {
        int b = g >> 6, ch = g & 63;
        int pg = t >> 5, fi = t & 31;
        const float* base = pe_part + (size_t)b * 256 * 2048 + ch * 32 + fi;
        float a0 = 0.f, a1 = 0.f, a2 = 0.f, a3 = 0.f;
#pragma unroll
        for (int p = pg; p < 256; p += 32) {
            a0 += base[(size_t)p * 2048];
            a1 += base[(size_t)(p + 8) * 2048];
            a2 += base[(size_t)(p + 16) * 2048];
            a3 += base[(size_t)(p + 24) * 2048];
        }
        __shared__ float red[8][32];
        red[pg][fi] = (a0 + a1) + (a2 + a3);
        __syncthreads();
        if (t < 32) {
            float s = red[0][t];
#pragma unroll
            for (int i = 1; i < 8; ++i) s += red[i][t];
            S_sum[(size_t)b * 2048 + ch * 32 + t] = s;
        }
    } else {
        int b = g - 256;
        if (t < C_) {
            const float* vp = vsum_part + (size_t)b * 256 * C_ + t;
            float a0 = 0.f, a1 = 0.f, a2 = 0.f, a3 = 0.f;
#pragma unroll
            for (int i = 0; i < 256; i += 4) {
                a0 += vp[(size_t)(i + 0) * C_];
                a1 += vp[(size_t)(i + 1) * C_];
                a2 += vp[(size_t)(i + 2) * C_];
                a3 += vp[(size_t)(i + 3) * C_];
            }
            vsum_final[b * C_ + t] = (a0 + a1) + (a2 + a3);
        }
    }
}

// ========== kB2: SW2 = ((vsum-excl)@Wv + S_sum) @ w_sa2 ==========
__global__ __launch_bounds__(256) void kB2(const float* __restrict__ v,
                                           const float* __restrict__ Wv,
                                           const float* __restrict__ vsum_final,
                                           const float* __restrict__ S_sum,
                                           const float* __restrict__ w2,
                                           float* __restrict__ SW2) {
    int b = blockIdx.x >> 3, seg = blockIdx.x & 7;   // 32 blocks
    int t = threadIdx.x;
    __shared__ float vd[4][C_];
    __shared__ float Sl[4][CN_];
#pragma unroll
    for (int mlp = 0; mlp < 2; ++mlp) {
        int ml = (t >> 7) + mlp * 2;
        int c = t & 127;
        int m = seg * 4 + ml;
        float excl = 0.f;
        if (m > 16) {
            for (int r = 0; r < m - 16; ++r) excl += v[((size_t)b * N_ + r) * C_ + c];
        } else if (m < 16) {
            for (int r = N_ - (16 - m); r < N_; ++r) excl += v[((size_t)b * N_ + r) * C_ + c];
        }
        vd[ml][c] = vsum_final[b * C_ + c] - excl;
    }
    __syncthreads();
    {
        int ml = t >> 6, c2 = t & 63;
        float s = 0.f;
        for (int c = 0; c < C_; ++c) s += vd[ml][c] * Wv[c * CN_ + c2];
        s += S_sum[(size_t)b * 2048 + (seg * 4 + ml) * CN_ + c2];
        Sl[ml][c2] = s;
    }
    __syncthreads();
#pragma unroll
    for (int pass = 0; pass < 2; ++pass) {
        int ml = (t >> 7) + pass * 2;
        int cc = t & 127;
        float s = 0.f;
#pragma unroll
        for (int c2 = 0; c2 < CN_; ++c2) s += Sl[ml][c2] * w2[c2 * C_ + cc];
        SW2[((size_t)b * M_ + seg * 4 + ml) * C_ + cc] = s;
    }
}

// ========== kOut2: out = scores @ SW2 ==========
__global__ __launch_bounds__(256) void kOut2(const float* __restrict__ scl_g,
                                             const float* __restrict__ SW2,
                                             float* __restrict__ out) {
    int g = blockIdx.x;        // 512 blocks: 128 per b, 64 rows each
    int b = g >> 7;
    int n0 = (g & 127) * 64;
    int t = threadIdx.x;
    int lane = t & 63, wv = t >> 6;
    __shared__ float scl[64][M_];

    {
        const f4* src = (const f4*)(scl_g + ((size_t)b * N_ + (size_t)n0) * M_);
        f4* dst = (f4*)&scl[0][0];
        dst[t] = src[t];
        dst[256 + t] = src[256 + t];
    }
    f2 sw2[M_];
    {
        const f2* sw2g = (const f2*)(SW2 + (size_t)b * M_ * C_);
#pragma unroll
        for (int mm = 0; mm < M_; ++mm) sw2[mm] = sw2g[mm * 64 + lane];
    }
    __syncthreads();
    for (int i = 0; i < 16; ++i) {
        int r = wv * 16 + i;
        const f4* sp = (const f4*)(&scl[r][0]);
        float ox = 0.f, oy = 0.f;
#pragma unroll
        for (int j4 = 0; j4 < 8; ++j4) {
            f4 s4 = sp[j4];
            ox += s4.x * sw2[j4 * 4 + 0].x; oy += s4.x * sw2[j4 * 4 + 0].y;
            ox += s4.y * sw2[j4 * 4 + 1].x; oy += s4.y * sw2[j4 * 4 + 1].y;
            ox += s4.z * sw2[j4 * 4 + 2].x; oy += s4.z * sw2[j4 * 4 + 2].y;
            ox += s4.w * sw2[j4 * 4 + 3].x; oy += s4.w * sw2[j4 * 4 + 3].y;
        }
        size_t u = (size_t)b * N_ + (size_t)(n0 + r);
        f2 o; o.x = ox; o.y = oy;
        *((f2*)(out + u * C_) + lane) = o;
    }
}

extern "C" void kernel_launch(void* const* d_in, const int* in_sizes, int n_in,
                              void* d_out, int out_size, void* d_ws, size_t ws_size,
                              hipStream_t stream) {
    const float* q  = (const float*)d_in[0];
    const float* k  = (const float*)d_in[1];
    const float* v  = (const float*)d_in[2];
    const float* pe = (const float*)d_in[3];
    const float* Wq = (const float*)d_in[4];
    const float* Wk = (const float*)d_in[5];
    const float* Wv = (const float*)d_in[6];
    const float* w1 = (const float*)d_in[7];
    const float* w2 = (const float*)d_in[8];
    float* out = (float*)d_out;
    float* ws  = (float*)d_ws;

    // workspace layout (floats)
    float* vsum_part  = ws;                          // 1024*128  = 131072
    float* vsum_final = vsum_part + 131072;          // 512
    float* scl_g      = vsum_final + 512;            // 4*8192*32 = 1048576
    float* pe_part    = scl_g + 1048576;             // 1024*2048 = 2097152
    float* S_sum      = pe_part + 2097152;           // 8192
    float* SW2        = S_sum + 8192;                // 16384

    kA   <<<1024, 256, 0, stream>>>(q, k, v, pe, Wq, Wk, w1, vsum_part, scl_g, pe_part);
    kR   <<<260, 256, 0, stream>>>(pe_part, vsum_part, S_sum, vsum_final);
    kB2  <<<32, 256, 0, stream>>>(v, Wv, vsum_final, S_sum, w2, SW2);
    kOut2<<<512, 256, 0, stream>>>(scl_g, SW2, out);
}

// Round 14
// 92.839 us; speedup vs baseline: 1.9943x; 1.9943x over previous
//
#include <hip/hip_runtime.h>
#include <math.h>

#define B_ 4
#define N_ 8192
#define C_ 128
#define CN_ 64
#define M_ 32

#define ROR1 0x121
#define ROR2 0x122
#define ROR4 0x124
#define ROR8 0x128

typedef float f4 __attribute__((ext_vector_type(4)));
typedef float f2 __attribute__((ext_vector_type(2)));

__device__ __forceinline__ f4 ld4(const float* p) { return *(const f4*)p; }
__device__ __forceinline__ f4 ntld4(const float* p) {
    return __builtin_nontemporal_load((const f4*)p);
}

template<int CTRL>
__device__ __forceinline__ float dpp_add(float x) {
    int y = __builtin_amdgcn_update_dpp(0, __float_as_int(x), CTRL, 0xF, 0xF, true);
    return x + __int_as_float(y);
}
template<int CTRL>
__device__ __forceinline__ float dpp_max(float x) {
    int y = __builtin_amdgcn_update_dpp(0, __float_as_int(x), CTRL, 0xF, 0xF, true);
    return fmaxf(x, __int_as_float(y));
}
__device__ __forceinline__ float red16_add(float x) {
    return dpp_add<ROR1>(dpp_add<ROR2>(dpp_add<ROR4>(dpp_add<ROR8>(x))));
}
__device__ __forceinline__ float red16_max(float x) {
    return dpp_max<ROR1>(dpp_max<ROR2>(dpp_max<ROR4>(dpp_max<ROR8>(x))));
}

// ========== kA: [0,1024) self-contained pe blocks | [1024,1280) vsum partials ==========
__global__ __launch_bounds__(256) void kA(const float* __restrict__ q,
                                          const float* __restrict__ k,
                                          const float* __restrict__ v,
                                          const float* __restrict__ pe,
                                          const float* __restrict__ Wq,
                                          const float* __restrict__ Wk,
                                          const float* __restrict__ w1,
                                          float* __restrict__ vsum_part,
                                          float* __restrict__ scl_g,
                                          float* __restrict__ pe_part) {
    __shared__ float lpd[4][256];              // 4 KB pdot staging
    __shared__ __align__(16) f4 lps4[4][256];  // 16 KB cross-wave reduce / vsum red
    __shared__ float pro[352];                 // wq1[128] wk1[128] aL[32] kbL[64]

    int g = blockIdx.x;
    int t = threadIdx.x;
    int lane = t & 63, wv = t >> 6;

    if (g < 1024) {
        int b = g >> 8;
        int n0 = (g & 255) * 32;
        int grp = lane >> 4, li = lane & 15;
        float* wq1l = pro;
        float* wk1l = pro + 128;
        float* aL   = pro + 256;
        float* kbL  = pro + 288;

        // ---- fold weights (L2-resident) ----
        if (t < C_) {
            float s = 0.f;
            for (int c2 = 0; c2 < CN_; ++c2) s += Wq[t * CN_ + c2] * w1[c2];
            wq1l[t] = s;
        } else {
            int c = t - C_;
            float s = 0.f;
            for (int c2 = 0; c2 < CN_; ++c2) s += Wk[c * CN_ + c2] * w1[c2];
            wk1l[c] = s;
        }
        __syncthreads();

        // ---- per-block a[32] (rows n0..n0+31) and kb[64] (rows n0-16..n0+47) ----
        {
            f4 wk0 = *((const f4*)wk1l + li * 2);
            f4 wk1v = *((const f4*)wk1l + li * 2 + 1);
#pragma unroll
            for (int it = 0; it < 4; ++it) {
                int rl = wv * 16 + it * 4 + grp;       // 0..63
                int jrow = n0 - 16 + rl;
                float tk = 0.f;
                if (jrow >= 0 && jrow < N_) {
                    const float* kr = k + ((size_t)b * N_ + jrow) * C_;
                    f4 y0 = ld4(kr + li * 8), y1 = ld4(kr + li * 8 + 4);
                    tk = y0.x * wk0.x + y0.y * wk0.y + y0.z * wk0.z + y0.w * wk0.w
                       + y1.x * wk1v.x + y1.y * wk1v.y + y1.z * wk1v.z + y1.w * wk1v.w;
                }
                tk = red16_add(tk);
                if (li == 0) kbL[rl] = tk;
            }
            f4 wq0 = *((const f4*)wq1l + li * 2);
            f4 wq1v = *((const f4*)wq1l + li * 2 + 1);
#pragma unroll
            for (int it = 0; it < 2; ++it) {
                int rl = wv * 8 + it * 4 + grp;        // 0..31
                const float* qr = q + ((size_t)b * N_ + n0 + rl) * C_;
                f4 x0 = ld4(qr + li * 8), x1 = ld4(qr + li * 8 + 4);
                float ta = x0.x * wq0.x + x0.y * wq0.y + x0.z * wq0.z + x0.w * wq0.w
                         + x1.x * wq1v.x + x1.y * wq1v.y + x1.z * wq1v.z + x1.w * wq1v.w;
                ta = red16_add(ta);
                if (li == 0) aL[rl] = ta;
            }
        }
        __syncthreads();

        // ---- pe stream: 8 rows/wave, x[8] in flight, NON-TEMPORAL pe loads ----
        f4 w1v = *((const f4*)w1 + li);
        f4 acc[8];
#pragma unroll
        for (int j = 0; j < 8; ++j) acc[j] = (f4){0.f, 0.f, 0.f, 0.f};

        int nbase = n0 + wv * 8;
        const float* pbase = pe + ((size_t)b * N_ + (size_t)nbase) * 2048;
        for (int i = 0; i < 8; ++i) {
            const float* p = pbase + (size_t)i * 2048;
            f4 x[8];
#pragma unroll
            for (int j = 0; j < 8; ++j) x[j] = ntld4(p + (j * 64 + lane) * 4);
#pragma unroll
            for (int j = 0; j < 8; ++j) {
                acc[j] += x[j];
                float tv = x[j].x * w1v.x + x[j].y * w1v.y + x[j].z * w1v.z + x[j].w * w1v.w;
                tv = red16_add(tv);
                if (li == 0) lpd[wv][i * 32 + j * 4 + grp] = tv;
            }
        }

        // ---- fused softmax (wave-local; aL/kbL from LDS) ----
        {
            int hw = lane >> 5, m = lane & 31;
            float* sout = scl_g + ((size_t)b * N_ + (size_t)nbase) * M_;
#pragma unroll
            for (int ii = 0; ii < 4; ++ii) {
                int rl = ii * 2 + hw;                   // wave-local row 0..7
                int rb = wv * 8 + rl;                   // block-local row 0..31
                float pd = lpd[wv][rl * 32 + m];
                float lg = aL[rb] + pd - kbL[rb + m];
                float mx = red16_max(lg);
                mx = fmaxf(mx, __shfl_xor(mx, 16));
                float e = __expf(lg - mx);
                float sm = red16_add(e);
                sm += __shfl_xor(sm, 16);
                sout[ii * 64 + lane] = e / sm;
            }
        }

        // ---- cross-wave reduce -> pe_part[g] (two 16KB rounds, R8-proven) ----
        f4* ppg = (f4*)(pe_part + (size_t)g * 2048);
#pragma unroll
        for (int r = 0; r < 2; ++r) {
            __syncthreads();
#pragma unroll
            for (int jr = 0; jr < 4; ++jr) lps4[wv][jr * 64 + lane] = acc[r * 4 + jr];
            __syncthreads();
            f4 s = lps4[0][t];
            s += lps4[1][t];
            s += lps4[2][t];
            s += lps4[3][t];
            ppg[r * 256 + t] = s;
        }
    } else {
        // ---- vsum partials: 256 blocks, 128 rows each ----
        int gg = g - 1024;
        int b = gg >> 6;
        int chunk = gg & 63;
        const float* vb = v + ((size_t)b * N_ + (size_t)chunk * 128) * C_;
        int c4 = t & 31, h = t >> 5;
        f4 acc = (f4){0.f, 0.f, 0.f, 0.f};
        for (int r = h; r < 128; r += 8) acc += ld4(vb + (size_t)r * C_ + c4 * 4);
        f4* red = &lps4[0][0];
        red[t] = acc;
        __syncthreads();
        if (t < 32) {
            f4 s = red[t];
#pragma unroll
            for (int i = 1; i < 8; ++i) s += red[i * 32 + t];
            *((f4*)(vsum_part + (size_t)gg * C_) + t) = s;
        }
    }
}

// ========== kR: parallel reduce: S_sum[b,2048] over 256 partials ; vsum_final ==========
__global__ __launch_bounds__(256) void kR(const float* __restrict__ pe_part,
                                          const float* __restrict__ vsum_part,
                                          float* __restrict__ S_sum,
                                          float* __restrict__ vsum_final) {
    int g = blockIdx.x;
    int t = threadIdx.x;
    if (g < 256) {
        int b = g >> 6, ch = g & 63;
        int pg = t >> 5, fi = t & 31;
        const float* base = pe_part + (size_t)b * 256 * 2048 + ch * 32 + fi;
        float a0 = 0.f, a1 = 0.f, a2 = 0.f, a3 = 0.f;
#pragma unroll
        for (int p = pg; p < 256; p += 32) {
            a0 += base[(size_t)p * 2048];
            a1 += base[(size_t)(p + 8) * 2048];
            a2 += base[(size_t)(p + 16) * 2048];
            a3 += base[(size_t)(p + 24) * 2048];
        }
        __shared__ float red[8][32];
        red[pg][fi] = (a0 + a1) + (a2 + a3);
        __syncthreads();
        if (t < 32) {
            float s = red[0][t];
#pragma unroll
            for (int i = 1; i < 8; ++i) s += red[i][t];
            S_sum[(size_t)b * 2048 + ch * 32 + t] = s;
        }
    } else {
        int b = g - 256;
        if (t < C_) {
            const float* vp = vsum_part + (size_t)b * 64 * C_ + t;
            float a0 = 0.f, a1 = 0.f, a2 = 0.f, a3 = 0.f;
#pragma unroll
            for (int i = 0; i < 64; i += 4) {
                a0 += vp[(i + 0) * C_];
                a1 += vp[(i + 1) * C_];
                a2 += vp[(i + 2) * C_];
                a3 += vp[(i + 3) * C_];
            }
            vsum_final[b * C_ + t] = (a0 + a1) + (a2 + a3);
        }
    }
}

// ========== kB2: SW2 = ((vsum-excl)@Wv + S_sum) @ w_sa2 ==========
__global__ __launch_bounds__(256) void kB2(const float* __restrict__ v,
                                           const float* __restrict__ Wv,
                                           const float* __restrict__ vsum_final,
                                           const float* __restrict__ S_sum,
                                           const float* __restrict__ w2,
                                           float* __restrict__ SW2) {
    int b = blockIdx.x >> 3, seg = blockIdx.x & 7;   // 32 blocks
    int t = threadIdx.x;
    __shared__ float vd[4][C_];
    __shared__ float Sl[4][CN_];
#pragma unroll
    for (int mlp = 0; mlp < 2; ++mlp) {
        int ml = (t >> 7) + mlp * 2;
        int c = t & 127;
        int m = seg * 4 + ml;
        float excl = 0.f;
        if (m > 16) {
            for (int r = 0; r < m - 16; ++r) excl += v[((size_t)b * N_ + r) * C_ + c];
        } else if (m < 16) {
            for (int r = N_ - (16 - m); r < N_; ++r) excl += v[((size_t)b * N_ + r) * C_ + c];
        }
        vd[ml][c] = vsum_final[b * C_ + c] - excl;
    }
    __syncthreads();
    {
        int ml = t >> 6, c2 = t & 63;
        float s = 0.f;
        for (int c = 0; c < C_; ++c) s += vd[ml][c] * Wv[c * CN_ + c2];
        s += S_sum[(size_t)b * 2048 + (seg * 4 + ml) * CN_ + c2];
        Sl[ml][c2] = s;
    }
    __syncthreads();
#pragma unroll
    for (int pass = 0; pass < 2; ++pass) {
        int ml = (t >> 7) + pass * 2;
        int cc = t & 127;
        float s = 0.f;
#pragma unroll
        for (int c2 = 0; c2 < CN_; ++c2) s += Sl[ml][c2] * w2[c2 * C_ + cc];
        SW2[((size_t)b * M_ + seg * 4 + ml) * C_ + cc] = s;
    }
}

// ========== kOut2: out = scores @ SW2 ==========
__global__ __launch_bounds__(256) void kOut2(const float* __restrict__ scl_g,
                                             const float* __restrict__ SW2,
                                             float* __restrict__ out) {
    int g = blockIdx.x;        // 512 blocks: 128 per b, 64 rows each
    int b = g >> 7;
    int n0 = (g & 127) * 64;
    int t = threadIdx.x;
    int lane = t & 63, wv = t >> 6;
    __shared__ float scl[64][M_];

    {
        const f4* src = (const f4*)(scl_g + ((size_t)b * N_ + (size_t)n0) * M_);
        f4* dst = (f4*)&scl[0][0];
        dst[t] = src[t];
        dst[256 + t] = src[256 + t];
    }
    f2 sw2[M_];
    {
        const f2* sw2g = (const f2*)(SW2 + (size_t)b * M_ * C_);
#pragma unroll
        for (int mm = 0; mm < M_; ++mm) sw2[mm] = sw2g[mm * 64 + lane];
    }
    __syncthreads();
    for (int i = 0; i < 16; ++i) {
        int r = wv * 16 + i;
        const f4* sp = (const f4*)(&scl[r][0]);
        float ox = 0.f, oy = 0.f;
#pragma unroll
        for (int j4 = 0; j4 < 8; ++j4) {
            f4 s4 = sp[j4];
            ox += s4.x * sw2[j4 * 4 + 0].x; oy += s4.x * sw2[j4 * 4 + 0].y;
            ox += s4.y * sw2[j4 * 4 + 1].x; oy += s4.y * sw2[j4 * 4 + 1].y;
            ox += s4.z * sw2[j4 * 4 + 2].x; oy += s4.z * sw2[j4 * 4 + 2].y;
            ox += s4.w * sw2[j4 * 4 + 3].x; oy += s4.w * sw2[j4 * 4 + 3].y;
        }
        size_t u = (size_t)b * N_ + (size_t)(n0 + r);
        f2 o; o.x = ox; o.y = oy;
        *((f2*)(out + u * C_) + lane) = o;
    }
}

extern "C" void kernel_launch(void* const* d_in, const int* in_sizes, int n_in,
                              void* d_out, int out_size, void* d_ws, size_t ws_size,
                              hipStream_t stream) {
    const float* q  = (const float*)d_in[0];
    const float* k  = (const float*)d_in[1];
    const float* v  = (const float*)d_in[2];
    const float* pe = (const float*)d_in[3];
    const float* Wq = (const float*)d_in[4];
    const float* Wk = (const float*)d_in[5];
    const float* Wv = (const float*)d_in[6];
    const float* w1 = (const float*)d_in[7];
    const float* w2 = (const float*)d_in[8];
    float* out = (float*)d_out;
    float* ws  = (float*)d_ws;

    // workspace layout (floats)
    float* vsum_part  = ws;                          // 256*128   = 32768
    float* vsum_final = vsum_part + 32768;           // 512
    float* scl_g      = vsum_final + 512;            // 4*8192*32 = 1048576
    float* pe_part    = scl_g + 1048576;             // 1024*2048 = 2097152
    float* S_sum      = pe_part + 2097152;           // 8192
    float* SW2        = S_sum + 8192;                // 16384

    kA   <<<1280, 256, 0, stream>>>(q, k, v, pe, Wq, Wk, w1, vsum_part, scl_g, pe_part);
    kR   <<<260, 256, 0, stream>>>(pe_part, vsum_part, S_sum, vsum_final);
    kB2  <<<32, 256, 0, stream>>>(v, Wv, vsum_final, S_sum, w2, SW2);
    kOut2<<<512, 256, 0, stream>>>(scl_g, SW2, out);
}

// Round 15
// 90.784 us; speedup vs baseline: 2.0394x; 1.0226x over previous
//
#include <hip/hip_runtime.h>
#include <math.h>

#define B_ 4
#define N_ 8192
#define C_ 128
#define CN_ 64
#define M_ 32

#define ROR1 0x121
#define ROR2 0x122
#define ROR4 0x124
#define ROR8 0x128

typedef float f4 __attribute__((ext_vector_type(4)));
typedef float f2 __attribute__((ext_vector_type(2)));

__device__ __forceinline__ f4 ld4(const float* p) { return *(const f4*)p; }
__device__ __forceinline__ f4 ntld4(const float* p) {
    return __builtin_nontemporal_load((const f4*)p);
}

template<int CTRL>
__device__ __forceinline__ float dpp_add(float x) {
    int y = __builtin_amdgcn_update_dpp(0, __float_as_int(x), CTRL, 0xF, 0xF, true);
    return x + __int_as_float(y);
}
template<int CTRL>
__device__ __forceinline__ float dpp_max(float x) {
    int y = __builtin_amdgcn_update_dpp(0, __float_as_int(x), CTRL, 0xF, 0xF, true);
    return fmaxf(x, __int_as_float(y));
}
__device__ __forceinline__ float red16_add(float x) {
    return dpp_add<ROR1>(dpp_add<ROR2>(dpp_add<ROR4>(dpp_add<ROR8>(x))));
}
__device__ __forceinline__ float red16_max(float x) {
    return dpp_max<ROR1>(dpp_max<ROR2>(dpp_max<ROR4>(dpp_max<ROR8>(x))));
}

// ========== kA: [0,1024) self-contained pe blocks | [1024,1280) vsum partials ==========
__global__ __launch_bounds__(256) void kA(const float* __restrict__ q,
                                          const float* __restrict__ k,
                                          const float* __restrict__ v,
                                          const float* __restrict__ pe,
                                          const float* __restrict__ Wq,
                                          const float* __restrict__ Wk,
                                          const float* __restrict__ w1,
                                          float* __restrict__ vsum_part,
                                          float* __restrict__ scl_g,
                                          float* __restrict__ pe_part) {
    __shared__ float lpd[4][256];              // 4 KB pdot staging
    __shared__ __align__(16) f4 lps4[4][256];  // 16 KB cross-wave reduce / vsum red
    __shared__ float pro[352];                 // wq1[128] wk1[128] aL[32] kbL[64]

    int g = blockIdx.x;
    int t = threadIdx.x;
    int lane = t & 63, wv = t >> 6;

    if (g < 1024) {
        int b = g >> 8;
        int n0 = (g & 255) * 32;
        int grp = lane >> 4, li = lane & 15;
        float* wq1l = pro;
        float* wk1l = pro + 128;
        float* aL   = pro + 256;
        float* kbL  = pro + 288;

        // ---- fold weights (L2-resident) ----
        if (t < C_) {
            float s = 0.f;
            for (int c2 = 0; c2 < CN_; ++c2) s += Wq[t * CN_ + c2] * w1[c2];
            wq1l[t] = s;
        } else {
            int c = t - C_;
            float s = 0.f;
            for (int c2 = 0; c2 < CN_; ++c2) s += Wk[c * CN_ + c2] * w1[c2];
            wk1l[c] = s;
        }
        __syncthreads();

        // ---- per-block a[32] (rows n0..n0+31) and kb[64] (rows n0-16..n0+47), NT loads ----
        {
            f4 wk0 = *((const f4*)wk1l + li * 2);
            f4 wk1v = *((const f4*)wk1l + li * 2 + 1);
#pragma unroll
            for (int it = 0; it < 4; ++it) {
                int rl = wv * 16 + it * 4 + grp;       // 0..63
                int jrow = n0 - 16 + rl;
                float tk = 0.f;
                if (jrow >= 0 && jrow < N_) {
                    const float* kr = k + ((size_t)b * N_ + jrow) * C_;
                    f4 y0 = ntld4(kr + li * 8), y1 = ntld4(kr + li * 8 + 4);
                    tk = y0.x * wk0.x + y0.y * wk0.y + y0.z * wk0.z + y0.w * wk0.w
                       + y1.x * wk1v.x + y1.y * wk1v.y + y1.z * wk1v.z + y1.w * wk1v.w;
                }
                tk = red16_add(tk);
                if (li == 0) kbL[rl] = tk;
            }
            f4 wq0 = *((const f4*)wq1l + li * 2);
            f4 wq1v = *((const f4*)wq1l + li * 2 + 1);
#pragma unroll
            for (int it = 0; it < 2; ++it) {
                int rl = wv * 8 + it * 4 + grp;        // 0..31
                const float* qr = q + ((size_t)b * N_ + n0 + rl) * C_;
                f4 x0 = ntld4(qr + li * 8), x1 = ntld4(qr + li * 8 + 4);
                float ta = x0.x * wq0.x + x0.y * wq0.y + x0.z * wq0.z + x0.w * wq0.w
                         + x1.x * wq1v.x + x1.y * wq1v.y + x1.z * wq1v.z + x1.w * wq1v.w;
                ta = red16_add(ta);
                if (li == 0) aL[rl] = ta;
            }
        }
        __syncthreads();

        // ---- pe stream: 8 rows/wave, x[8] in flight, NT loads ----
        f4 w1v = *((const f4*)w1 + li);
        f4 acc[8];
#pragma unroll
        for (int j = 0; j < 8; ++j) acc[j] = (f4){0.f, 0.f, 0.f, 0.f};

        int nbase = n0 + wv * 8;
        const float* pbase = pe + ((size_t)b * N_ + (size_t)nbase) * 2048;
        for (int i = 0; i < 8; ++i) {
            const float* p = pbase + (size_t)i * 2048;
            f4 x[8];
#pragma unroll
            for (int j = 0; j < 8; ++j) x[j] = ntld4(p + (j * 64 + lane) * 4);
#pragma unroll
            for (int j = 0; j < 8; ++j) {
                acc[j] += x[j];
                float tv = x[j].x * w1v.x + x[j].y * w1v.y + x[j].z * w1v.z + x[j].w * w1v.w;
                tv = red16_add(tv);
                if (li == 0) lpd[wv][i * 32 + j * 4 + grp] = tv;
            }
        }

        // ---- fused softmax (wave-local; aL/kbL from LDS) ----
        {
            int hw = lane >> 5, m = lane & 31;
            float* sout = scl_g + ((size_t)b * N_ + (size_t)nbase) * M_;
#pragma unroll
            for (int ii = 0; ii < 4; ++ii) {
                int rl = ii * 2 + hw;                   // wave-local row 0..7
                int rb = wv * 8 + rl;                   // block-local row 0..31
                float pd = lpd[wv][rl * 32 + m];
                float lg = aL[rb] + pd - kbL[rb + m];
                float mx = red16_max(lg);
                mx = fmaxf(mx, __shfl_xor(mx, 16));
                float e = __expf(lg - mx);
                float sm = red16_add(e);
                sm += __shfl_xor(sm, 16);
                sout[ii * 64 + lane] = e / sm;
            }
        }

        // ---- cross-wave reduce -> pe_part[g] (two 16KB rounds) ----
        f4* ppg = (f4*)(pe_part + (size_t)g * 2048);
#pragma unroll
        for (int r = 0; r < 2; ++r) {
            __syncthreads();
#pragma unroll
            for (int jr = 0; jr < 4; ++jr) lps4[wv][jr * 64 + lane] = acc[r * 4 + jr];
            __syncthreads();
            f4 s = lps4[0][t];
            s += lps4[1][t];
            s += lps4[2][t];
            s += lps4[3][t];
            ppg[r * 256 + t] = s;
        }
    } else {
        // ---- vsum partials: 256 blocks, 128 rows each, NT loads ----
        int gg = g - 1024;
        int b = gg >> 6;
        int chunk = gg & 63;
        const float* vb = v + ((size_t)b * N_ + (size_t)chunk * 128) * C_;
        int c4 = t & 31, h = t >> 5;
        f4 acc = (f4){0.f, 0.f, 0.f, 0.f};
        for (int r = h; r < 128; r += 8) acc += ntld4(vb + (size_t)r * C_ + c4 * 4);
        f4* red = &lps4[0][0];
        red[t] = acc;
        __syncthreads();
        if (t < 32) {
            f4 s = red[t];
#pragma unroll
            for (int i = 1; i < 8; ++i) s += red[i * 32 + t];
            *((f4*)(vsum_part + (size_t)gg * C_) + t) = s;
        }
    }
}

// ========== kR: parallel reduce: S_sum[b,2048] over 256 partials ; vsum_final ==========
__global__ __launch_bounds__(256) void kR(const float* __restrict__ pe_part,
                                          const float* __restrict__ vsum_part,
                                          float* __restrict__ S_sum,
                                          float* __restrict__ vsum_final) {
    int g = blockIdx.x;
    int t = threadIdx.x;
    if (g < 256) {
        int b = g >> 6, ch = g & 63;
        int pg = t >> 5, fi = t & 31;
        const float* base = pe_part + (size_t)b * 256 * 2048 + ch * 32 + fi;
        float a0 = 0.f, a1 = 0.f, a2 = 0.f, a3 = 0.f;
#pragma unroll
        for (int p = pg; p < 256; p += 32) {
            a0 += base[(size_t)p * 2048];
            a1 += base[(size_t)(p + 8) * 2048];
            a2 += base[(size_t)(p + 16) * 2048];
            a3 += base[(size_t)(p + 24) * 2048];
        }
        __shared__ float red[8][32];
        red[pg][fi] = (a0 + a1) + (a2 + a3);
        __syncthreads();
        if (t < 32) {
            float s = red[0][t];
#pragma unroll
            for (int i = 1; i < 8; ++i) s += red[i][t];
            S_sum[(size_t)b * 2048 + ch * 32 + t] = s;
        }
    } else {
        int b = g - 256;
        if (t < C_) {
            const float* vp = vsum_part + (size_t)b * 64 * C_ + t;
            float a0 = 0.f, a1 = 0.f, a2 = 0.f, a3 = 0.f;
#pragma unroll
            for (int i = 0; i < 64; i += 4) {
                a0 += vp[(i + 0) * C_];
                a1 += vp[(i + 1) * C_];
                a2 += vp[(i + 2) * C_];
                a3 += vp[(i + 3) * C_];
            }
            vsum_final[b * C_ + t] = (a0 + a1) + (a2 + a3);
        }
    }
}

// ========== kB2: SW2 = ((vsum-excl)@Wv + S_sum) @ w_sa2 ==========
__global__ __launch_bounds__(256) void kB2(const float* __restrict__ v,
                                           const float* __restrict__ Wv,
                                           const float* __restrict__ vsum_final,
                                           const float* __restrict__ S_sum,
                                           const float* __restrict__ w2,
                                           float* __restrict__ SW2) {
    int b = blockIdx.x >> 3, seg = blockIdx.x & 7;   // 32 blocks
    int t = threadIdx.x;
    __shared__ float vd[4][C_];
    __shared__ float Sl[4][CN_];
#pragma unroll
    for (int mlp = 0; mlp < 2; ++mlp) {
        int ml = (t >> 7) + mlp * 2;
        int c = t & 127;
        int m = seg * 4 + ml;
        float excl = 0.f;
        if (m > 16) {
            for (int r = 0; r < m - 16; ++r) excl += v[((size_t)b * N_ + r) * C_ + c];
        } else if (m < 16) {
            for (int r = N_ - (16 - m); r < N_; ++r) excl += v[((size_t)b * N_ + r) * C_ + c];
        }
        vd[ml][c] = vsum_final[b * C_ + c] - excl;
    }
    __syncthreads();
    {
        int ml = t >> 6, c2 = t & 63;
        float s = 0.f;
        for (int c = 0; c < C_; ++c) s += vd[ml][c] * Wv[c * CN_ + c2];
        s += S_sum[(size_t)b * 2048 + (seg * 4 + ml) * CN_ + c2];
        Sl[ml][c2] = s;
    }
    __syncthreads();
#pragma unroll
    for (int pass = 0; pass < 2; ++pass) {
        int ml = (t >> 7) + pass * 2;
        int cc = t & 127;
        float s = 0.f;
#pragma unroll
        for (int c2 = 0; c2 < CN_; ++c2) s += Sl[ml][c2] * w2[c2 * C_ + cc];
        SW2[((size_t)b * M_ + seg * 4 + ml) * C_ + cc] = s;
    }
}

// ========== kOut2: out = scores @ SW2 (NT store) ==========
__global__ __launch_bounds__(256) void kOut2(const float* __restrict__ scl_g,
                                             const float* __restrict__ SW2,
                                             float* __restrict__ out) {
    int g = blockIdx.x;        // 512 blocks: 128 per b, 64 rows each
    int b = g >> 7;
    int n0 = (g & 127) * 64;
    int t = threadIdx.x;
    int lane = t & 63, wv = t >> 6;
    __shared__ float scl[64][M_];

    {
        const f4* src = (const f4*)(scl_g + ((size_t)b * N_ + (size_t)n0) * M_);
        f4* dst = (f4*)&scl[0][0];
        dst[t] = src[t];
        dst[256 + t] = src[256 + t];
    }
    f2 sw2[M_];
    {
        const f2* sw2g = (const f2*)(SW2 + (size_t)b * M_ * C_);
#pragma unroll
        for (int mm = 0; mm < M_; ++mm) sw2[mm] = sw2g[mm * 64 + lane];
    }
    __syncthreads();
    for (int i = 0; i < 16; ++i) {
        int r = wv * 16 + i;
        const f4* sp = (const f4*)(&scl[r][0]);
        float ox = 0.f, oy = 0.f;
#pragma unroll
        for (int j4 = 0; j4 < 8; ++j4) {
            f4 s4 = sp[j4];
            ox += s4.x * sw2[j4 * 4 + 0].x; oy += s4.x * sw2[j4 * 4 + 0].y;
            ox += s4.y * sw2[j4 * 4 + 1].x; oy += s4.y * sw2[j4 * 4 + 1].y;
            ox += s4.z * sw2[j4 * 4 + 2].x; oy += s4.z * sw2[j4 * 4 + 2].y;
            ox += s4.w * sw2[j4 * 4 + 3].x; oy += s4.w * sw2[j4 * 4 + 3].y;
        }
        size_t u = (size_t)b * N_ + (size_t)(n0 + r);
        f2 o; o.x = ox; o.y = oy;
        __builtin_nontemporal_store(o, (f2*)(out + u * C_) + lane);
    }
}

extern "C" void kernel_launch(void* const* d_in, const int* in_sizes, int n_in,
                              void* d_out, int out_size, void* d_ws, size_t ws_size,
                              hipStream_t stream) {
    const float* q  = (const float*)d_in[0];
    const float* k  = (const float*)d_in[1];
    const float* v  = (const float*)d_in[2];
    const float* pe = (const float*)d_in[3];
    const float* Wq = (const float*)d_in[4];
    const float* Wk = (const float*)d_in[5];
    const float* Wv = (const float*)d_in[6];
    const float* w1 = (const float*)d_in[7];
    const float* w2 = (const float*)d_in[8];
    float* out = (float*)d_out;
    float* ws  = (float*)d_ws;

    // workspace layout (floats)
    float* vsum_part  = ws;                          // 256*128   = 32768
    float* vsum_final = vsum_part + 32768;           // 512
    float* scl_g      = vsum_final + 512;            // 4*8192*32 = 1048576
    float* pe_part    = scl_g + 1048576;             // 1024*2048 = 2097152
    float* S_sum      = pe_part + 2097152;           // 8192
    float* SW2        = S_sum + 8192;                // 16384

    kA   <<<1280, 256, 0, stream>>>(q, k, v, pe, Wq, Wk, w1, vsum_part, scl_g, pe_part);
    kR   <<<260, 256, 0, stream>>>(pe_part, vsum_part, S_sum, vsum_final);
    kB2  <<<32, 256, 0, stream>>>(v, Wv, vsum_final, S_sum, w2, SW2);
    kOut2<<<512, 256, 0, stream>>>(scl_g, SW2, out);
}